// Round 8
// baseline (350.325 us; speedup 1.0000x reference)
//
#include <hip/hip_runtime.h>

#define DIM 144
#define ROWS 64
#define TILE_ELEMS (ROWS * DIM)        // 9216 floats per tile
#define TILE_F4 (TILE_ELEMS / 4)       // 2304 float4 per tile
#define NT 512                         // threads per block (8 waves)
#define PERSIST_BLOCKS 1024            // 4 blocks/CU on 256 CUs -> 32 waves/CU

// Workgroup barrier WITHOUT the vmcnt(0) drain of __syncthreads().
// All three sync points have LDS-only dependencies -> lgkmcnt(0) suffices.
#define BARRIER_LGKM()                                            \
    do {                                                          \
        asm volatile("s_waitcnt lgkmcnt(0)" ::: "memory");        \
        __builtin_amdgcn_s_barrier();                             \
        asm volatile("" ::: "memory");                            \
    } while (0)

// ---------------------------------------------------------------------------
// Kernel 1: build Cw[9][16][16] — per-(l,t)-unit 16x16 mixing matrices.
// C[p][v][u] = mixing[k, i0, j0] * norm[i0, j0] * weight[k]
// ---------------------------------------------------------------------------
__global__ __launch_bounds__(256) void build_C(
    const float* __restrict__ weight,
    const float* __restrict__ mixing,
    const float* __restrict__ norm,
    float* __restrict__ Cw)
{
    int idx = blockIdx.x * 256 + threadIdx.x;   // 0 .. 2303
    if (idx >= 9 * 256) return;
    int p  = idx >> 8;          // unit 0..8
    int vu = idx & 255;
    int v = vu >> 4, u = vu & 15;
    int l, t, off;
    if (p == 0)      { l = 0; t = 0;     off = 0;  }
    else if (p < 4)  { l = 1; t = p - 1; off = 16; }
    else             { l = 2; t = p - 4; off = 64; }
    int d  = 2 * l + 1;
    int k  = l * 256 + v * 16 + u;
    int i0 = off + v * d + t;
    int j0 = off + u * d + t;
    float m  = mixing[(size_t)k * (DIM * DIM) + i0 * DIM + j0];
    float nc = norm[i0 * DIM + j0];
    Cw[idx] = m * nc * weight[k];
}

// ---------------------------------------------------------------------------
// Kernel 2: persistent transpose-mix-transpose, register-LEAN (target: fit
// the 32-VGPR budget of __launch_bounds__(512,8) with ZERO scratch).
// Evidence: (512,8) is the only config reaching 85% occupancy / 2.84 TB/s
// (r4/r5); its spills were the structure's fault (5 concurrent float4 live).
// Here staging is a hand-rolled depth-3 rolling stream: peak live ~20-24
// VGPRs in every phase. 36 KB LDS -> 4 blocks/CU = 32 waves/CU.
// LDS layout (XOR swizzle): addr(col,row) = col*64 + (row ^ (col>>2))
//   compute phase (lane=row): XOR bijection -> exactly 2 lanes/bank, free.
// ---------------------------------------------------------------------------
__device__ __forceinline__ void unit_params(int p, int& d, int& t, int& off) {
    int l;
    if (p == 0)      { l = 0; t = 0;     off = 0;  }
    else if (p < 4)  { l = 1; t = p - 1; off = 16; }
    else             { l = 2; t = p - 4; off = 64; }
    d = 2 * l + 1;
}

// Swizzled LDS store of one float4 (columns 4c..4c+3 of row `row`).
__device__ __forceinline__ void lds_store_f4(float* buf, int e4, float4 v) {
    int row = e4 / 36;
    int c   = e4 - row * 36;           // float4-column 0..35
    float* p = &buf[(4 * c) * 64 + (row ^ c)];
    p[0]   = v.x;
    p[64]  = v.y;
    p[128] = v.z;
    p[192] = v.w;
}

__global__ __launch_bounds__(NT, 8) void tp_linear_kernel(
    const float4* __restrict__ feat4,
    const float* __restrict__ Cw,
    float4* __restrict__ out4,
    long long total4,
    int tiles)
{
    __shared__ float buf[DIM * 64];
    const int tid = threadIdx.x;
    const int nb  = gridDim.x;
    const int r   = tid & 63;
    const int w   = tid >> 6;          // wave 0..7

    for (int t = blockIdx.x; t < tiles; t += nb) {
        const long long base4 = (long long)t * TILE_F4;
        const bool full = (base4 + TILE_F4 <= total4);

        // ---- stage in: depth-3 rolling load->LDS stream (<=3 float4 live) ----
        // e4 = i*NT + tid, i = 0..4; i=4 valid only for tid < 256.
        if (full) {
            float4 v0 = feat4[base4 + 0 * NT + tid];
            float4 v1 = feat4[base4 + 1 * NT + tid];
            float4 v2 = feat4[base4 + 2 * NT + tid];
            lds_store_f4(buf, 0 * NT + tid, v0);
            v0 = feat4[base4 + 3 * NT + tid];
            lds_store_f4(buf, 1 * NT + tid, v1);
            if (tid < TILE_F4 - 4 * NT)            // tid < 256
                v1 = feat4[base4 + 4 * NT + tid];
            lds_store_f4(buf, 2 * NT + tid, v2);
            lds_store_f4(buf, 3 * NT + tid, v0);
            if (tid < TILE_F4 - 4 * NT)
                lds_store_f4(buf, 4 * NT + tid, v1);
        } else {
            // Partial tile (cold): same rolling shape, per-load guards, so the
            // register frame stays as lean as the hot path.
            auto ldp = [&](int i) -> float4 {
                int e4 = i * NT + tid;
                long long g = base4 + e4;
                return (e4 < TILE_F4 && g < total4)
                           ? feat4[g] : make_float4(0.f, 0.f, 0.f, 0.f);
            };
            float4 v0 = ldp(0);
            float4 v1 = ldp(1);
            float4 v2 = ldp(2);
            lds_store_f4(buf, 0 * NT + tid, v0);
            v0 = ldp(3);
            lds_store_f4(buf, 1 * NT + tid, v1);
            v1 = ldp(4);
            lds_store_f4(buf, 2 * NT + tid, v2);
            lds_store_f4(buf, 3 * NT + tid, v0);
            if (tid < TILE_F4 - 4 * NT)
                lds_store_f4(buf, 4 * NT + tid, v1);
        }

        BARRIER_LGKM();   // A: stage-in ds_writes visible

        // ---- compute: wave w owns units {w, w+8}; lane = row ----
        // Streamed write-back: one accumulator scalar live at a time.
        for (int p = w; p < 9; p += 8) {
            int d, tt, off;
            unit_params(p, d, tt, off);
            const float* __restrict__ C = Cw + p * 256;  // wave-uniform -> s_load

            float fin[16];
#pragma unroll
            for (int u = 0; u < 16; ++u) {
                int col = off + u * d + tt;
                fin[u] = buf[col * 64 + (r ^ (col >> 2))];
            }
#pragma unroll
            for (int vv = 0; vv < 16; ++vv) {
                float a = 0.0f;
#pragma unroll
                for (int u = 0; u < 16; ++u)
                    a += C[vv * 16 + u] * fin[u];
                int col = off + vv * d + tt;
                buf[col * 64 + (r ^ (col >> 2))] = a;
            }
        }

        BARRIER_LGKM();   // B: compute writes visible before stage-out reads

        // ---- stage out: streamed (one float4 live), coalesced stores ----
#pragma unroll
        for (int i = 0; i < 5; ++i) {
            int e4 = i * NT + tid;
            if (e4 < TILE_F4) {                     // wave-uniform for i<4
                int row = e4 / 36;
                int c   = e4 - row * 36;
                const float* p = &buf[(4 * c) * 64 + (row ^ c)];
                float4 o = make_float4(p[0], p[64], p[128], p[192]);
                if (full) {
                    out4[base4 + e4] = o;
                } else {
                    long long g = base4 + e4;
                    if (g < total4) out4[g] = o;
                }
            }
        }

        BARRIER_LGKM();   // C: stage-out reads done before buf overwrite
    }
}

extern "C" void kernel_launch(void* const* d_in, const int* in_sizes, int n_in,
                              void* d_out, int out_size, void* d_ws, size_t ws_size,
                              hipStream_t stream)
{
    const float* feat   = (const float*)d_in[0];   // [B, 144]
    const float* weight = (const float*)d_in[1];   // [768]
    const float* mixing = (const float*)d_in[2];   // [768, 144, 144]
    const float* norm   = (const float*)d_in[3];   // [144, 144]
    float* out = (float*)d_out;
    float* Cw  = (float*)d_ws;                     // 9*256 floats

    long long total  = (long long)in_sizes[0];     // B * 144
    long long total4 = total / 4;                  // 144 % 4 == 0
    int nrows = (int)(total / DIM);
    int tiles = (nrows + ROWS - 1) / ROWS;
    int nb    = tiles < PERSIST_BLOCKS ? tiles : PERSIST_BLOCKS;

    build_C<<<9, 256, 0, stream>>>(weight, mixing, norm, Cw);
    tp_linear_kernel<<<nb, NT, 0, stream>>>(
        (const float4*)feat, Cw, (float4*)out, total4, tiles);
}